// Round 8
// baseline (487.538 us; speedup 1.0000x reference)
//
#include <hip/hip_runtime.h>
#include <stdint.h>

#define NG 4
#define NK 160
#define GD 128
#define ED 512
#define BB 16
#define TT 4096
static constexpr size_t ZSZ = (size_t)BB * ED * TT;           // 33554432

typedef float f32x16 __attribute__((ext_vector_type(16)));
typedef float f32x4 __attribute__((ext_vector_type(4)));

// d_out FLOAT32: [0,ZSZ) z_q | [ZSZ] loss | codes after.
// ws (floats): [0,1024) bsum | [1024,1664) sc | [2048, 2048+81920) ct[g][d][k]

// ---------------- prep: transpose codebook to [g][d][k] + codeword norms ---
__global__ void prep_kernel(const float* __restrict__ cb, float* __restrict__ sc,
                            float* __restrict__ ct) {
  int i = blockIdx.x * 256 + threadIdx.x;                 // 81920 total
  int g = i / (GD * NK), r = i % (GD * NK), d = r / NK, k = r % NK;
  ct[i] = cb[((size_t)g * NK + k) * GD + d];
  if (i < NG * NK) {
    const float* c = cb + (size_t)i * GD;
    float s = 0.f;
    for (int dd = 0; dd < GD; ++dd) s = fmaf(c[dd], c[dd], s);
    sc[i] = s;
  }
}

// ---- scalar-memory chunk load: 20 codes for one d into SGPRs -------------
#define SLOAD(C0, C1, BASE, OFF)                                          \
  asm volatile("s_load_dwordx16 %0, %2, %3\n\t"                           \
               "s_load_dwordx4  %1, %2, %4"                               \
               : "=s"(C0), "=s"(C1)                                       \
               : "s"(BASE), "s"(OFF), "s"((OFF) + 64u))

// wait: lgkmcnt(0) (SMEM is out-of-order -> only 0 is safe), with dataflow
// ties so FMAs cannot be hoisted above the wait (rule #18).
#define SWAIT(C0, C1, XV)                                                 \
  asm volatile("s_waitcnt lgkmcnt(0)"                                     \
               : "+s"(C0), "+s"(C1), "+v"(XV) :: "memory")

#define FMA20(C0, C1, XV)                                                 \
  do {                                                                    \
    _Pragma("unroll") for (int j = 0; j < 16; ++j) {                      \
      float cv = (C0)[j];                                                 \
      acc[0][j] = fmaf((XV)[0], cv, acc[0][j]);                           \
      acc[1][j] = fmaf((XV)[1], cv, acc[1][j]);                           \
      acc[2][j] = fmaf((XV)[2], cv, acc[2][j]);                           \
      acc[3][j] = fmaf((XV)[3], cv, acc[3][j]);                           \
    }                                                                     \
    _Pragma("unroll") for (int j = 0; j < 4; ++j) {                       \
      float cv = (C1)[j];                                                 \
      acc[0][16 + j] = fmaf((XV)[0], cv, acc[0][16 + j]);                 \
      acc[1][16 + j] = fmaf((XV)[1], cv, acc[1][16 + j]);                 \
      acc[2][16 + j] = fmaf((XV)[2], cv, acc[2][16 + j]);                 \
      acc[3][16 + j] = fmaf((XV)[3], cv, acc[3][16 + j]);                 \
    }                                                                     \
  } while (0)

// ---------------- main: 256 tokens/block, 8 waves x 20 codes --------------
__global__ __launch_bounds__(512, 2) void vq_kernel(const float* __restrict__ xin,
                                                    const float* __restrict__ cb,
                                                    const float* __restrict__ sc,
                                                    const float* __restrict__ ct,
                                                    float* __restrict__ out,
                                                    float* __restrict__ bsum) {
  __shared__ __align__(16) float xs[GD * 256];            // 128 KB, [d][tok]

  const int tid = threadIdx.x;
  const int w = tid >> 6;                                 // wave 0..7
  const int l = tid & 63;
  const int g = (int)(blockIdx.x >> 8);
  const int widx = (int)(blockIdx.x & 255);
  const int b = widx >> 4;
  const int t0 = (widx & 15) << 8;                        // 256-token window

  // ---- stage x [d][256 tok], coalesced: 8192 float4 total, 16 per thread --
  const float* xbase = xin + ((size_t)(b * ED + g * GD)) * TT + t0;
#pragma unroll 8
  for (int i = 0; i < 16; ++i) {
    int idx = i * 512 + tid;                              // float4 index
    int d = idx >> 6, col = idx & 63;
    *(f32x4*)&xs[d * 256 + col * 4] =
        *(const f32x4*)(xbase + (size_t)d * TT + col * 4);
  }
  __syncthreads();

  // ---- sx for this lane's 4 tokens (ascending-d chain, ref parity) ----
  float sxv[4] = {0.f, 0.f, 0.f, 0.f};
  for (int d = 0; d < GD; ++d) {
    f32x4 v = *(const f32x4*)&xs[d * 256 + l * 4];
#pragma unroll
    for (int i = 0; i < 4; ++i) sxv[i] = fmaf(v[i], v[i], sxv[i]);
  }

  // ---- SGPR-operand GEMM: wave w owns codes [w*20, w*20+20) ----
  const uint64_t ctg = (uint64_t)(uintptr_t)(ct + (size_t)g * GD * NK);
  const uint32_t sw = (uint32_t)__builtin_amdgcn_readfirstlane(w);
  uint32_t soff = sw * 80u;                               // byte off, d=0 chunk

  float acc[4][20];
#pragma unroll
  for (int i = 0; i < 4; ++i)
#pragma unroll
    for (int j = 0; j < 20; ++j) acc[i][j] = 0.f;

  f32x16 cA0, cB0;
  f32x4 cA1, cB1, xvA, xvB;

  SLOAD(cA0, cA1, ctg, soff); soff += 640u;
  xvA = *(const f32x4*)&xs[l * 4];                        // d=0
  for (int d2 = 0; d2 < 63; ++d2) {
    SWAIT(cA0, cA1, xvA);
    SLOAD(cB0, cB1, ctg, soff); soff += 640u;
    xvB = *(const f32x4*)&xs[(2 * d2 + 1) * 256 + l * 4];
    FMA20(cA0, cA1, xvA);
    SWAIT(cB0, cB1, xvB);
    SLOAD(cA0, cA1, ctg, soff); soff += 640u;
    xvA = *(const f32x4*)&xs[(2 * d2 + 2) * 256 + l * 4];
    FMA20(cB0, cB1, xvB);
  }
  SWAIT(cA0, cA1, xvA);                                   // d = 126
  SLOAD(cB0, cB1, ctg, soff);
  xvB = *(const f32x4*)&xs[127 * 256 + l * 4];
  FMA20(cA0, cA1, xvA);
  SWAIT(cB0, cB1, xvB);                                   // d = 127
  FMA20(cB0, cB1, xvB);

  // ---- per-wave argmin over its 20 codes (ascending k, strict <) ----
  const float* scw = sc + g * NK + w * 20;
  float best[4] = {3.4e38f, 3.4e38f, 3.4e38f, 3.4e38f};
  int bik[4] = {0, 0, 0, 0};
#pragma unroll
  for (int j = 0; j < 20; ++j) {
    float scv = scw[j];
#pragma unroll
    for (int i = 0; i < 4; ++i) {
      float dv = (sxv[i] + scv) - 2.0f * acc[i][j];       // ref formula order
      if (dv < best[i]) { best[i] = dv; bik[i] = w * 20 + j; }
    }
  }

  // ---- cross-wave merge via reused xs ----
  __syncthreads();                                        // xs reads done
  float* bestW = xs;                                      // [8][256]
  int* bikW = (int*)(xs + 2048);                          // [8][256]
  f32x4 bv = {best[0], best[1], best[2], best[3]};
  *(f32x4*)&bestW[w * 256 + l * 4] = bv;
#pragma unroll
  for (int i = 0; i < 4; ++i) bikW[w * 256 + l * 4 + i] = bik[i];
  __syncthreads();

  if (tid < 256) {                                        // token owner = tid
    float bf = bestW[tid];
    int kf = bikW[tid];
#pragma unroll
    for (int ww = 1; ww < 8; ++ww) {                      // ascending k order
      float bw = bestW[ww * 256 + tid];
      int kw = bikW[ww * 256 + tid];
      if (bw < bf) { bf = bw; kf = kw; }                  // first-min kept
    }

    // codes_out[b, g, t0+tid]
    out[ZSZ + 1 + ((size_t)(b * NG + g)) * TT + t0 + tid] = (float)kf;

    // z_q_out[b, g*128+d, t0+tid] = codebook[g, kf, d]
    const f32x4* cw = (const f32x4*)(cb + ((size_t)g * NK + kf) * GD);
    float* zbase = out + ((size_t)(b * ED + g * GD)) * TT + t0 + tid;
#pragma unroll 4
    for (int d4 = 0; d4 < 32; ++d4) {
      f32x4 v = cw[d4];
      zbase[(size_t)(4 * d4 + 0) * TT] = v[0];
      zbase[(size_t)(4 * d4 + 1) * TT] = v[1];
      zbase[(size_t)(4 * d4 + 2) * TT] = v[2];
      zbase[(size_t)(4 * d4 + 3) * TT] = v[3];
    }

    // loss partial: deterministic wave reduce (waves 0..3)
    float s = bf;
#pragma unroll
    for (int off = 32; off > 0; off >>= 1) s += __shfl_down(s, off, 64);
    if (l == 0) xs[4096 + w] = s;
  }
  __syncthreads();
  if (tid == 0)
    bsum[blockIdx.x] = ((xs[4096] + xs[4097]) + xs[4098]) + xs[4099];
}

// ---------------- loss ----------------
__global__ __launch_bounds__(64) void loss_kernel(const float* __restrict__ bsum,
                                                  float* __restrict__ out) {
  float s = 0.f;
  for (int j = 0; j < 16; ++j) s += bsum[threadIdx.x + 64 * j];
#pragma unroll
  for (int off = 32; off > 0; off >>= 1) s += __shfl_down(s, off, 64);
  if (threadIdx.x == 0) out[ZSZ] = 1.25f * s / (float)ZSZ;
}

extern "C" void kernel_launch(void* const* d_in, const int* in_sizes, int n_in,
                              void* d_out, int out_size, void* d_ws, size_t ws_size,
                              hipStream_t stream) {
  const float* xin = (const float*)d_in[0];
  const float* cb  = (const float*)d_in[1];
  float* out  = (float*)d_out;
  float* bsum = (float*)d_ws;            // 1024
  float* sc   = (float*)d_ws + 1024;     // 640
  float* ct   = (float*)d_ws + 2048;     // 81920

  prep_kernel<<<320, 256, 0, stream>>>(cb, sc, ct);
  vq_kernel<<<1024, 512, 0, stream>>>(xin, cb, sc, ct, out, bsum);
  loss_kernel<<<1, 64, 0, stream>>>(bsum, out);
}

// Round 9
// 185.809 us; speedup vs baseline: 2.6239x; 2.6239x over previous
//
#include <hip/hip_runtime.h>
#include <stdint.h>

#define NG 4
#define NK 160
#define GD 128
#define ED 512
#define BB 16
#define TT 4096
#define BK 32
#define BTOK 256
static constexpr size_t ZSZ = (size_t)BB * ED * TT;           // 33554432

typedef float f32x4 __attribute__((ext_vector_type(4)));
typedef float f32x2 __attribute__((ext_vector_type(2)));

// d_out FLOAT32: [0,ZSZ) z_q | [ZSZ] loss | codes after.
// ws (floats): [0,1024) bsum | [1024,1664) sc | [2048, 2048+81920) ct[g][d][k]

// ---------------- prep: transpose codebook to [g][d][k] + codeword norms ---
__global__ void prep_kernel(const float* __restrict__ cb, float* __restrict__ sc,
                            float* __restrict__ ct) {
  int i = blockIdx.x * 256 + threadIdx.x;                 // 81920 total
  int g = i / (GD * NK), r = i % (GD * NK), d = r / NK, k = r % NK;
  ct[i] = cb[((size_t)g * NK + k) * GD + d];
  if (i < NG * NK) {
    const float* c = cb + (size_t)i * GD;
    float s = 0.f;
    for (int dd = 0; dd < GD; ++dd) s = fmaf(c[dd], c[dd], s);
    sc[i] = s;
  }
}

// ---------------- main: 256 tokens x 160 codes per block, TM=16 TN=10 ------
__global__ __launch_bounds__(256, 2) void vq_kernel(const float* __restrict__ xin,
                                                    const float* __restrict__ cb,
                                                    const float* __restrict__ sc,
                                                    const float* __restrict__ ct,
                                                    float* __restrict__ out,
                                                    float* __restrict__ bsum) {
  __shared__ __align__(16) float smem[BK * BTOK + BK * NK];  // 53248 B
  __shared__ float sxs[BTOK];
  __shared__ float wred[4];
  float* xs = smem;                                       // [BK][256]
  float* cs = smem + BK * BTOK;                           // [BK][160]

  const int tid = (int)threadIdx.x;
  const int ty = tid >> 4, tx = tid & 15;                 // thread (ty,tx)
  const int g = (int)(blockIdx.x >> 8);
  const int tb = (int)(blockIdx.x & 255);
  const int b = tb >> 4;
  const int t0 = (tb & 15) << 8;                          // 256-token window

  const float* xbase = xin + ((size_t)(b * ED + g * GD)) * TT + t0;
  const float* ctg = ct + (size_t)g * GD * NK;

  float acc[16][10];
#pragma unroll
  for (int i = 0; i < 16; ++i)
#pragma unroll
    for (int j = 0; j < 10; ++j) acc[i][j] = 0.f;
  float sxa = 0.f;

  for (int k0 = 0; k0 < GD; k0 += BK) {                   // 4 K-slices
    __syncthreads();                                      // prev reads done
    // stage xs [BK][256]: 2048 f32x4, 8 per thread, coalesced along t
#pragma unroll
    for (int i = 0; i < 8; ++i) {
      int q = i * 256 + tid;
      int dd = q >> 6, col = (q & 63) << 2;
      *(f32x4*)&xs[dd * BTOK + col] =
          *(const f32x4*)(xbase + (size_t)(k0 + dd) * TT + col);
    }
    // stage cs [BK][160]: 1280 f32x4, 5 per thread, coalesced along k
#pragma unroll
    for (int i = 0; i < 5; ++i) {
      int q = i * 256 + tid;
      int dd = q / 40, col = (q - dd * 40) << 2;
      *(f32x4*)&cs[dd * NK + col] =
          *(const f32x4*)(ctg + (size_t)(k0 + dd) * NK + col);
    }
    __syncthreads();

    // sx partial for token t0+tid (ascending-d chain, parity with r3-r6)
    for (int dd = 0; dd < BK; ++dd) {
      float v = xs[dd * BTOK + tid];
      sxa = fmaf(v, v, sxa);
    }

    // register-tile FMA: 16 tokens x 10 codes per thread
    for (int dd = 0; dd < BK; ++dd) {
      f32x4 xv[4];
#pragma unroll
      for (int u = 0; u < 4; ++u)
        xv[u] = *(const f32x4*)&xs[dd * BTOK + ty * 16 + u * 4];
      f32x2 cv[5];
#pragma unroll
      for (int u = 0; u < 5; ++u)
        cv[u] = *(const f32x2*)&cs[dd * NK + tx * 10 + u * 2];
#pragma unroll
      for (int i4 = 0; i4 < 4; ++i4)
#pragma unroll
        for (int e = 0; e < 4; ++e) {
          const float xf = xv[i4][e];
          const int i = i4 * 4 + e;
#pragma unroll
          for (int jq = 0; jq < 5; ++jq) {
            acc[i][2 * jq + 0] = fmaf(xf, cv[jq][0], acc[i][2 * jq + 0]);
            acc[i][2 * jq + 1] = fmaf(xf, cv[jq][1], acc[i][2 * jq + 1]);
          }
        }
    }
  }

  // ---- per-thread argmin over its 10 codes for its 16 tokens ----
  float scv[10];
#pragma unroll
  for (int j = 0; j < 10; ++j) scv[j] = sc[g * NK + tx * 10 + j];
  sxs[tid] = sxa;                                         // token t0+tid
  __syncthreads();                                        // sxs ready; k-loop done

  float best[16];
  int bik[16];
#pragma unroll
  for (int i = 0; i < 16; ++i) {
    best[i] = 3.4e38f;
    bik[i] = 0;
    const float sx = sxs[ty * 16 + i];
#pragma unroll
    for (int j = 0; j < 10; ++j) {
      const float dk = (sx + scv[j]) - 2.0f * acc[i][j];  // ref formula order
      if (dk < best[i]) { best[i] = dk; bik[i] = tx * 10 + j; }
    }
  }

  // ---- cross-thread merge (ascending tx = ascending code index) ----
  float* bestA = smem;                                    // [16 tx][256 tok]
  int* bikA = (int*)(smem + 16 * 256);
#pragma unroll
  for (int i = 0; i < 16; ++i) {
    bestA[tx * 256 + ty * 16 + i] = best[i];
    bikA[tx * 256 + ty * 16 + i] = bik[i];
  }
  __syncthreads();

  float bf = bestA[tid];
  int kf = bikA[tid];
#pragma unroll
  for (int w2 = 1; w2 < 16; ++w2) {
    float bw = bestA[w2 * 256 + tid];
    int kw = bikA[w2 * 256 + tid];
    if (bw < bf) { bf = bw; kf = kw; }                    // np first-index
  }

  // codes_out[b, g, t0+tid]
  out[ZSZ + 1 + ((size_t)(b * NG + g)) * TT + t0 + tid] = (float)kf;

  // z_q_out[b, g*128+d, t0+tid] = codebook[g, kf, d]
  const f32x4* cw = (const f32x4*)(cb + ((size_t)g * NK + kf) * GD);
  float* zbase = out + ((size_t)(b * ED + g * GD)) * TT + t0 + tid;
#pragma unroll 4
  for (int d4 = 0; d4 < 32; ++d4) {
    f32x4 v = cw[d4];
    zbase[(size_t)(4 * d4 + 0) * TT] = v[0];
    zbase[(size_t)(4 * d4 + 1) * TT] = v[1];
    zbase[(size_t)(4 * d4 + 2) * TT] = v[2];
    zbase[(size_t)(4 * d4 + 3) * TT] = v[3];
  }

  // loss partial: deterministic wave reduce + fixed-order block sum
  float s = bf;
#pragma unroll
  for (int off = 32; off > 0; off >>= 1) s += __shfl_down(s, off, 64);
  if ((tid & 63) == 0) wred[tid >> 6] = s;
  __syncthreads();
  if (tid == 0)
    bsum[blockIdx.x] = ((wred[0] + wred[1]) + wred[2]) + wred[3];
}

// ---------------- loss ----------------
__global__ __launch_bounds__(64) void loss_kernel(const float* __restrict__ bsum,
                                                  float* __restrict__ out) {
  float s = 0.f;
  for (int j = 0; j < 16; ++j) s += bsum[threadIdx.x + 64 * j];
#pragma unroll
  for (int off = 32; off > 0; off >>= 1) s += __shfl_down(s, off, 64);
  if (threadIdx.x == 0) out[ZSZ] = 1.25f * s / (float)ZSZ;
}

extern "C" void kernel_launch(void* const* d_in, const int* in_sizes, int n_in,
                              void* d_out, int out_size, void* d_ws, size_t ws_size,
                              hipStream_t stream) {
  const float* xin = (const float*)d_in[0];
  const float* cb  = (const float*)d_in[1];
  float* out  = (float*)d_out;
  float* bsum = (float*)d_ws;            // 1024
  float* sc   = (float*)d_ws + 1024;     // 640
  float* ct   = (float*)d_ws + 2048;     // 81920

  prep_kernel<<<320, 256, 0, stream>>>(cb, sc, ct);
  vq_kernel<<<1024, 256, 0, stream>>>(xin, cb, sc, ct, out, bsum);
  loss_kernel<<<1, 64, 0, stream>>>(bsum, out);
}

// Round 10
// 173.550 us; speedup vs baseline: 2.8092x; 1.0706x over previous
//
#include <hip/hip_runtime.h>
#include <stdint.h>

#define NG 4
#define NK 160
#define GD 128
#define ED 512
#define BB 16
#define TT 4096
#define BK 32
#define BTOK 256
static constexpr size_t ZSZ = (size_t)BB * ED * TT;           // 33554432

typedef float f32x4 __attribute__((ext_vector_type(4)));
typedef float f32x2 __attribute__((ext_vector_type(2)));

// d_out FLOAT32: [0,ZSZ) z_q | [ZSZ] loss | codes after.
// ws (floats): [0,1024) bsum | [1024,1664) sc | [2048, 2048+81920) ct[g][d][k]

// ---------------- prep: transpose codebook to [g][d][k] + codeword norms ---
__global__ void prep_kernel(const float* __restrict__ cb, float* __restrict__ sc,
                            float* __restrict__ ct) {
  int i = blockIdx.x * 256 + threadIdx.x;                 // 81920 total
  int g = i / (GD * NK), r = i % (GD * NK), d = r / NK, k = r % NK;
  ct[i] = cb[((size_t)g * NK + k) * GD + d];
  if (i < NG * NK) {
    const float* c = cb + (size_t)i * GD;
    float s = 0.f;
    for (int dd = 0; dd < GD; ++dd) s = fmaf(c[dd], c[dd], s);
    sc[i] = s;
  }
}

// ---------------- main: 256 tokens x 160 codes per block, TM=16 TN=10 ------
// waves_per_eu(2,2): pin occupancy at 2 waves/SIMD so the allocator has the
// full 256-VGPR budget -> acc[16][10] stays register-resident (r9 spilled).
__global__ __launch_bounds__(256)
__attribute__((amdgpu_waves_per_eu(2, 2)))
void vq_kernel(const float* __restrict__ xin,
               const float* __restrict__ cb,
               const float* __restrict__ sc,
               const float* __restrict__ ct,
               float* __restrict__ out,
               float* __restrict__ bsum) {
  __shared__ __align__(16) float smem[BK * BTOK + BK * NK];  // 53248 B
  __shared__ float sxs[BTOK];
  __shared__ float wred[4];
  float* xs = smem;                                       // [BK][256]
  float* cs = smem + BK * BTOK;                           // [BK][160]

  const int tid = (int)threadIdx.x;
  const int ty = tid >> 4, tx = tid & 15;                 // thread (ty,tx)
  const int g = (int)(blockIdx.x >> 8);
  const int tb = (int)(blockIdx.x & 255);
  const int b = tb >> 4;
  const int t0 = (tb & 15) << 8;                          // 256-token window

  const float* xbase = xin + ((size_t)(b * ED + g * GD)) * TT + t0;
  const float* ctg = ct + (size_t)g * GD * NK;

  float acc[16][10];
#pragma unroll
  for (int i = 0; i < 16; ++i)
#pragma unroll
    for (int j = 0; j < 10; ++j) acc[i][j] = 0.f;
  float sxa = 0.f;

  for (int k0 = 0; k0 < GD; k0 += BK) {                   // 4 K-slices
    __syncthreads();                                      // prev reads done
    // stage xs [BK][256]: 2048 f32x4, 8 per thread, coalesced along t
#pragma unroll
    for (int i = 0; i < 8; ++i) {
      int q = i * 256 + tid;
      int dd = q >> 6, col = (q & 63) << 2;
      *(f32x4*)&xs[dd * BTOK + col] =
          *(const f32x4*)(xbase + (size_t)(k0 + dd) * TT + col);
    }
    // stage cs [BK][160]: 1280 f32x4, 5 per thread, coalesced along k
#pragma unroll
    for (int i = 0; i < 5; ++i) {
      int q = i * 256 + tid;
      int dd = q / 40, col = (q - dd * 40) << 2;
      *(f32x4*)&cs[dd * NK + col] =
          *(const f32x4*)(ctg + (size_t)(k0 + dd) * NK + col);
    }
    __syncthreads();

    // sx partial for token t0+tid (ascending-d chain, parity with r3-r9)
    for (int dd = 0; dd < BK; ++dd) {
      float v = xs[dd * BTOK + tid];
      sxa = fmaf(v, v, sxa);
    }

    // register-tile FMA: 16 tokens x 10 codes per thread
    for (int dd = 0; dd < BK; ++dd) {
      f32x4 xv[4];
#pragma unroll
      for (int u = 0; u < 4; ++u)
        xv[u] = *(const f32x4*)&xs[dd * BTOK + ty * 16 + u * 4];
      f32x2 cv[5];
#pragma unroll
      for (int u = 0; u < 5; ++u)
        cv[u] = *(const f32x2*)&cs[dd * NK + tx * 10 + u * 2];
#pragma unroll
      for (int i4 = 0; i4 < 4; ++i4)
#pragma unroll
        for (int e = 0; e < 4; ++e) {
          const float xf = xv[i4][e];
          const int i = i4 * 4 + e;
#pragma unroll
          for (int jq = 0; jq < 5; ++jq) {
            acc[i][2 * jq + 0] = fmaf(xf, cv[jq][0], acc[i][2 * jq + 0]);
            acc[i][2 * jq + 1] = fmaf(xf, cv[jq][1], acc[i][2 * jq + 1]);
          }
        }
    }
  }

  // ---- per-thread argmin over its 10 codes for its 16 tokens ----
  float scv[10];
#pragma unroll
  for (int j = 0; j < 10; ++j) scv[j] = sc[g * NK + tx * 10 + j];
  sxs[tid] = sxa;                                         // token t0+tid
  __syncthreads();                                        // sxs ready; k-loop done

  float best[16];
  int bik[16];
#pragma unroll
  for (int i = 0; i < 16; ++i) {
    best[i] = 3.4e38f;
    bik[i] = 0;
    const float sx = sxs[ty * 16 + i];
#pragma unroll
    for (int j = 0; j < 10; ++j) {
      const float dk = (sx + scv[j]) - 2.0f * acc[i][j];  // ref formula order
      if (dk < best[i]) { best[i] = dk; bik[i] = tx * 10 + j; }
    }
  }

  // ---- cross-thread merge (ascending tx = ascending code index) ----
  // stride 257 kills the 16-way bank conflict of a 256 stride (r9: 1.8M cy)
  float* bestA = smem;                                    // [16 tx][257]
  int* bikA = (int*)(smem + 16 * 257);
#pragma unroll
  for (int i = 0; i < 16; ++i) {
    bestA[tx * 257 + ty * 16 + i] = best[i];
    bikA[tx * 257 + ty * 16 + i] = bik[i];
  }
  __syncthreads();

  float bf = bestA[tid];
  int kf = bikA[tid];
#pragma unroll
  for (int w2 = 1; w2 < 16; ++w2) {
    float bw = bestA[w2 * 257 + tid];
    int kw = bikA[w2 * 257 + tid];
    if (bw < bf) { bf = bw; kf = kw; }                    // np first-index
  }

  // codes_out[b, g, t0+tid]
  out[ZSZ + 1 + ((size_t)(b * NG + g)) * TT + t0 + tid] = (float)kf;

  // z_q_out[b, g*128+d, t0+tid] = codebook[g, kf, d]
  const f32x4* cw = (const f32x4*)(cb + ((size_t)g * NK + kf) * GD);
  float* zbase = out + ((size_t)(b * ED + g * GD)) * TT + t0 + tid;
#pragma unroll 4
  for (int d4 = 0; d4 < 32; ++d4) {
    f32x4 v = cw[d4];
    zbase[(size_t)(4 * d4 + 0) * TT] = v[0];
    zbase[(size_t)(4 * d4 + 1) * TT] = v[1];
    zbase[(size_t)(4 * d4 + 2) * TT] = v[2];
    zbase[(size_t)(4 * d4 + 3) * TT] = v[3];
  }

  // loss partial: deterministic wave reduce + fixed-order block sum
  float s = bf;
#pragma unroll
  for (int off = 32; off > 0; off >>= 1) s += __shfl_down(s, off, 64);
  if ((tid & 63) == 0) wred[tid >> 6] = s;
  __syncthreads();
  if (tid == 0)
    bsum[blockIdx.x] = ((wred[0] + wred[1]) + wred[2]) + wred[3];
}

// ---------------- loss ----------------
__global__ __launch_bounds__(64) void loss_kernel(const float* __restrict__ bsum,
                                                  float* __restrict__ out) {
  float s = 0.f;
  for (int j = 0; j < 16; ++j) s += bsum[threadIdx.x + 64 * j];
#pragma unroll
  for (int off = 32; off > 0; off >>= 1) s += __shfl_down(s, off, 64);
  if (threadIdx.x == 0) out[ZSZ] = 1.25f * s / (float)ZSZ;
}

extern "C" void kernel_launch(void* const* d_in, const int* in_sizes, int n_in,
                              void* d_out, int out_size, void* d_ws, size_t ws_size,
                              hipStream_t stream) {
  const float* xin = (const float*)d_in[0];
  const float* cb  = (const float*)d_in[1];
  float* out  = (float*)d_out;
  float* bsum = (float*)d_ws;            // 1024
  float* sc   = (float*)d_ws + 1024;     // 640
  float* ct   = (float*)d_ws + 2048;     // 81920

  prep_kernel<<<320, 256, 0, stream>>>(cb, sc, ct);
  vq_kernel<<<1024, 256, 0, stream>>>(xin, cb, sc, ct, out, bsum);
  loss_kernel<<<1, 64, 0, stream>>>(bsum, out);
}

// Round 11
// 143.911 us; speedup vs baseline: 3.3878x; 1.2060x over previous
//
#include <hip/hip_runtime.h>
#include <stdint.h>

#define NG 4
#define NK 160
#define GD 128
#define ED 512
#define BB 16
#define TT 4096
#define BK 32
#define BTOK 256
static constexpr size_t ZSZ = (size_t)BB * ED * TT;           // 33554432

typedef float f32x4 __attribute__((ext_vector_type(4)));

// d_out FLOAT32: [0,ZSZ) z_q | [ZSZ] loss | codes after.
// ws (floats): [0,1024) bsum | [1024,1664) sc | [2048, 2048+81920) ct[g][d][k]

// ---------------- prep: transpose codebook to [g][d][k] + codeword norms ---
__global__ void prep_kernel(const float* __restrict__ cb, float* __restrict__ sc,
                            float* __restrict__ ct) {
  int i = blockIdx.x * 256 + threadIdx.x;                 // 81920 total
  int g = i / (GD * NK), r = i % (GD * NK), d = r / NK, k = r % NK;
  ct[i] = cb[((size_t)g * NK + k) * GD + d];
  if (i < NG * NK) {
    const float* c = cb + (size_t)i * GD;
    float s = 0.f;
    for (int dd = 0; dd < GD; ++dd) s = fmaf(c[dd], c[dd], s);
    sc[i] = s;
  }
}

// ---------------- main: 512 threads, 8 waves x 20 codes, 4 tok/lane --------
// Wave w owns codes [w*20, w*20+20): code loads are wave-uniform (global,
// L2-hot, readfirstlane-derived -> scalarizable). x via 1 ds_read_b128/dd.
// acc[4][20] = 80 VGPR -> fits 128-VGPR budget, 4 waves/SIMD.
__global__ __launch_bounds__(512) void vq_kernel(const float* __restrict__ xin,
                                                 const float* __restrict__ cb,
                                                 const float* __restrict__ sc,
                                                 const float* __restrict__ ct,
                                                 float* __restrict__ out,
                                                 float* __restrict__ bsum) {
  __shared__ __align__(16) float xs[BK * BTOK];           // 32 KB, [dd][tok]
  __shared__ float wred[4];

  const int tid = (int)threadIdx.x;
  const int w = tid >> 6;                                 // wave 0..7
  const int l = tid & 63;                                 // lane
  const int g = (int)(blockIdx.x >> 8);
  const int tb = (int)(blockIdx.x & 255);
  const int b = tb >> 4;
  const int t0 = (tb & 15) << 8;                          // 256-token window

  const float* xbase = xin + ((size_t)(b * ED + g * GD)) * TT + t0;
  const float* ctg = ct + (size_t)g * GD * NK;
  const int kbase = __builtin_amdgcn_readfirstlane(w) * 20;  // wave-uniform

  float acc[4][20];
#pragma unroll
  for (int i = 0; i < 4; ++i)
#pragma unroll
    for (int j = 0; j < 20; ++j) acc[i][j] = 0.f;
  float sxa[4] = {0.f, 0.f, 0.f, 0.f};

  for (int k0 = 0; k0 < GD; k0 += BK) {                   // 4 K-slices
    __syncthreads();                                      // prev reads done
    // stage xs [BK][256]: 2048 f32x4, 4 per thread, coalesced along t
#pragma unroll
    for (int i = 0; i < 4; ++i) {
      int q = i * 512 + tid;
      int dd = q >> 6, col = (q & 63) << 2;
      *(f32x4*)&xs[dd * BTOK + col] =
          *(const f32x4*)(xbase + (size_t)(k0 + dd) * TT + col);
    }
    __syncthreads();

#pragma unroll 2
    for (int dd = 0; dd < BK; ++dd) {
      // this lane's 4 tokens (one b128, conflict-free)
      const f32x4 xv = *(const f32x4*)&xs[dd * BTOK + l * 4];
      // 20 codes at wave-uniform address (L2-hot broadcast)
      const float* cw = ctg + (size_t)(k0 + dd) * NK + kbase;
      const f32x4 c0 = *(const f32x4*)&cw[0];
      const f32x4 c1 = *(const f32x4*)&cw[4];
      const f32x4 c2 = *(const f32x4*)&cw[8];
      const f32x4 c3 = *(const f32x4*)&cw[12];
      const f32x4 c4 = *(const f32x4*)&cw[16];
      // sx chain (ascending dd, parity with r3-r10)
#pragma unroll
      for (int i = 0; i < 4; ++i) sxa[i] = fmaf(xv[i], xv[i], sxa[i]);
      // dot chains (ascending dd per (i,j), parity with r3-r10)
#pragma unroll
      for (int i = 0; i < 4; ++i) {
        const float xf = xv[i];
#pragma unroll
        for (int e = 0; e < 4; ++e) {
          acc[i][e] = fmaf(xf, c0[e], acc[i][e]);
          acc[i][4 + e] = fmaf(xf, c1[e], acc[i][4 + e]);
          acc[i][8 + e] = fmaf(xf, c2[e], acc[i][8 + e]);
          acc[i][12 + e] = fmaf(xf, c3[e], acc[i][12 + e]);
          acc[i][16 + e] = fmaf(xf, c4[e], acc[i][16 + e]);
        }
      }
    }
  }

  // ---- per-wave argmin over its 20 codes (ascending k, strict <) ----
  const float* scw = sc + g * NK + kbase;
  float best[4] = {3.4e38f, 3.4e38f, 3.4e38f, 3.4e38f};
  int bik[4] = {0, 0, 0, 0};
#pragma unroll
  for (int j = 0; j < 20; ++j) {
    const float scv = scw[j];
#pragma unroll
    for (int i = 0; i < 4; ++i) {
      const float dv = (sxa[i] + scv) - 2.0f * acc[i][j]; // ref formula order
      if (dv < best[i]) { best[i] = dv; bik[i] = kbase + j; }
    }
  }

  // ---- cross-wave merge via reused xs ----
  __syncthreads();                                        // xs reads done
  float* bestW = xs;                                      // [8][256]
  int* bikW = (int*)(xs + 2048);                          // [8][256]
  *(f32x4*)&bestW[w * 256 + l * 4] = (f32x4){best[0], best[1], best[2], best[3]};
#pragma unroll
  for (int i = 0; i < 4; ++i) bikW[w * 256 + l * 4 + i] = bik[i];
  __syncthreads();

  if (tid < 256) {                                        // token owner = tid
    float bf = bestW[tid];
    int kf = bikW[tid];
#pragma unroll
    for (int ww = 1; ww < 8; ++ww) {                      // ascending k order
      float bw = bestW[ww * 256 + tid];
      int kw = bikW[ww * 256 + tid];
      if (bw < bf) { bf = bw; kf = kw; }                  // first-min kept
    }

    // codes_out[b, g, t0+tid]
    out[ZSZ + 1 + ((size_t)(b * NG + g)) * TT + t0 + tid] = (float)kf;

    // z_q_out[b, g*128+d, t0+tid] = codebook[g, kf, d]
    const f32x4* cw = (const f32x4*)(cb + ((size_t)g * NK + kf) * GD);
    float* zbase = out + ((size_t)(b * ED + g * GD)) * TT + t0 + tid;
#pragma unroll 4
    for (int d4 = 0; d4 < 32; ++d4) {
      f32x4 v = cw[d4];
      zbase[(size_t)(4 * d4 + 0) * TT] = v[0];
      zbase[(size_t)(4 * d4 + 1) * TT] = v[1];
      zbase[(size_t)(4 * d4 + 2) * TT] = v[2];
      zbase[(size_t)(4 * d4 + 3) * TT] = v[3];
    }

    // loss partial: deterministic wave reduce (waves 0..3)
    float s = bf;
#pragma unroll
    for (int off = 32; off > 0; off >>= 1) s += __shfl_down(s, off, 64);
    if (l == 0) wred[w] = s;
  }
  __syncthreads();
  if (tid == 0)
    bsum[blockIdx.x] = ((wred[0] + wred[1]) + wred[2]) + wred[3];
}

// ---------------- loss ----------------
__global__ __launch_bounds__(64) void loss_kernel(const float* __restrict__ bsum,
                                                  float* __restrict__ out) {
  float s = 0.f;
  for (int j = 0; j < 16; ++j) s += bsum[threadIdx.x + 64 * j];
#pragma unroll
  for (int off = 32; off > 0; off >>= 1) s += __shfl_down(s, off, 64);
  if (threadIdx.x == 0) out[ZSZ] = 1.25f * s / (float)ZSZ;
}

extern "C" void kernel_launch(void* const* d_in, const int* in_sizes, int n_in,
                              void* d_out, int out_size, void* d_ws, size_t ws_size,
                              hipStream_t stream) {
  const float* xin = (const float*)d_in[0];
  const float* cb  = (const float*)d_in[1];
  float* out  = (float*)d_out;
  float* bsum = (float*)d_ws;            // 1024
  float* sc   = (float*)d_ws + 1024;     // 640
  float* ct   = (float*)d_ws + 2048;     // 81920

  prep_kernel<<<320, 256, 0, stream>>>(cb, sc, ct);
  vq_kernel<<<1024, 512, 0, stream>>>(xin, cb, sc, ct, out, bsum);
  loss_kernel<<<1, 64, 0, stream>>>(bsum, out);
}